// Round 2
// baseline (987.193 us; speedup 1.0000x reference)
//
#include <hip/hip_runtime.h>
#include <hip/hip_bf16.h>

typedef __bf16 bf8 __attribute__((ext_vector_type(8)));
typedef float f4 __attribute__((ext_vector_type(4)));
typedef unsigned short u16;
typedef unsigned int u32;

#define B_ 4
#define P_ 2048
#define D_ 768
#define H_ 12
#define HD_ 64
// scale * log2(e): exp(s*0.125) = exp2(s * 0.18033688)
#define EXPC_ 0.18033688011112042f

__device__ __forceinline__ u16 f2bf(float f) {  // RNE, for GEMM/LN outputs
  union { float f; u32 u; } c; c.f = f;
  u32 u = c.u;
  u += 0x7fffu + ((u >> 16) & 1u);
  return (u16)(u >> 16);
}

__device__ __forceinline__ float bf2f(u16 v) {
  union { u32 u; float f; } c; c.u = (u32)v << 16; return c.f;
}

// truncating pack of 4 floats -> 4 bf16 in a uint2 (cheap: shift/and/or)
__device__ __forceinline__ uint2 pack4(f4 v) {
  union { float f; u32 u; } a, b, c, d;
  a.f = v[0]; b.f = v[1]; c.f = v[2]; d.f = v[3];
  uint2 r;
  r.x = (a.u >> 16) | (b.u & 0xffff0000u);
  r.y = (c.u >> 16) | (d.u & 0xffff0000u);
  return r;
}

__device__ __forceinline__ f4 unpack4(ushort4 v) {
  f4 r;
  r[0] = bf2f(v.x); r[1] = bf2f(v.y); r[2] = bf2f(v.z); r[3] = bf2f(v.w);
  return r;
}

__device__ __forceinline__ f4 mfma16(bf8 a, bf8 b, f4 c) {
  return __builtin_amdgcn_mfma_f32_16x16x32_bf16(a, b, c, 0, 0, 0);
}

#define ZERO44(acc)                    \
  {                                    \
    f4 z_ = {0.f, 0.f, 0.f, 0.f};      \
    for (int i_ = 0; i_ < 4; ++i_)     \
      for (int j_ = 0; j_ < 4; ++j_)   \
        acc[i_][j_] = z_;              \
  }

// ---------------- transpose-cast fp32 (R,C) -> bf16 (C,R) ----------------
__global__ __launch_bounds__(256) void tcast_k(const float* __restrict__ src,
                                               u16* __restrict__ dst, int R, int C) {
  __shared__ float t[32][33];
  int c0 = blockIdx.x * 32, r0 = blockIdx.y * 32;
  int tx = threadIdx.x & 31, ty = threadIdx.x >> 5;  // 32 x 8
  #pragma unroll
  for (int i = 0; i < 32; i += 8) {
    int r = r0 + ty + i, c = c0 + tx;
    t[ty + i][tx] = (r < R && c < C) ? src[(size_t)r * C + c] : 0.f;
  }
  __syncthreads();
  #pragma unroll
  for (int i = 0; i < 32; i += 8) {
    int c = c0 + ty + i, r = r0 + tx;
    if (c < C && r < R) dst[(size_t)c * R + r] = f2bf(t[tx][ty + i]);
  }
}

// ---------------- layernorm fp32 -> bf16, one row (768) per block ----------------
__global__ __launch_bounds__(256) void ln_k(const float* __restrict__ x,
                                            const float* __restrict__ g,
                                            const float* __restrict__ b,
                                            u16* __restrict__ out) {
  int row = blockIdx.x;
  const float* xr = x + (size_t)row * D_;
  float v0 = xr[threadIdx.x], v1 = xr[threadIdx.x + 256], v2 = xr[threadIdx.x + 512];
  float s = v0 + v1 + v2;
  float s2 = v0 * v0 + v1 * v1 + v2 * v2;
  #pragma unroll
  for (int o = 32; o > 0; o >>= 1) {
    s += __shfl_down(s, o, 64);
    s2 += __shfl_down(s2, o, 64);
  }
  __shared__ float a[4], a2[4];
  int wv = threadIdx.x >> 6;
  if ((threadIdx.x & 63) == 0) { a[wv] = s; a2[wv] = s2; }
  __syncthreads();
  s = a[0] + a[1] + a[2] + a[3];
  s2 = a2[0] + a2[1] + a2[2] + a2[3];
  float mean = s * (1.f / 768.f);
  float var = s2 * (1.f / 768.f) - mean * mean;
  float rstd = rsqrtf(var + 1e-5f);
  u16* orow = out + (size_t)row * D_;
  float vv[3] = {v0, v1, v2};
  #pragma unroll
  for (int j = 0; j < 3; ++j) {
    int i = threadIdx.x + j * 256;
    orow[i] = f2bf((vv[j] - mean) * rstd * g[i] + b[i]);
  }
}

// ---------------- wave-level 64x64 GEMM core: C += A(M,K) * Bt(N,K)^T ----------------
template <int K>
__device__ __forceinline__ void wave_gemm(const u16* __restrict__ A, int lda,
                                          const u16* __restrict__ Bt, int ldb,
                                          f4 acc[4][4]) {
  const int lane = threadIdx.x & 63, l15 = lane & 15, quad = lane >> 4;
  #pragma unroll 2
  for (int k = 0; k < K; k += 32) {
    bf8 a[4], b[4];
    #pragma unroll
    for (int mt = 0; mt < 4; ++mt)
      a[mt] = *reinterpret_cast<const bf8*>(A + (size_t)(mt * 16 + l15) * lda + k + quad * 8);
    #pragma unroll
    for (int nt = 0; nt < 4; ++nt)
      b[nt] = *reinterpret_cast<const bf8*>(Bt + (size_t)(nt * 16 + l15) * ldb + k + quad * 8);
    #pragma unroll
    for (int mt = 0; mt < 4; ++mt)
      #pragma unroll
      for (int nt = 0; nt < 4; ++nt)
        acc[mt][nt] = mfma16(a[mt], b[nt], acc[mt][nt]);
  }
}

// ---------------- QKV GEMM: hln(8192,768) @ wT(2304,768)^T + bias -> Q,K,(V^T) bf16 ----------------
__global__ __launch_bounds__(256) void gemm_qkv_k(const u16* __restrict__ hln,
                                                  const u16* __restrict__ wT,
                                                  const float* __restrict__ bias,
                                                  u16* __restrict__ Q, u16* __restrict__ Km,
                                                  u16* __restrict__ Vt) {
  int wave = threadIdx.x >> 6;
  int m0 = blockIdx.y * 128 + (wave & 1) * 64;
  int n0 = blockIdx.x * 128 + (wave >> 1) * 64;
  f4 acc[4][4];
  ZERO44(acc);
  wave_gemm<768>(hln + (size_t)m0 * 768, 768, wT + (size_t)n0 * 768, 768, acc);
  int lane = threadIdx.x & 63, l15 = lane & 15, quad = lane >> 4;
  #pragma unroll
  for (int mt = 0; mt < 4; ++mt)
    #pragma unroll
    for (int nt = 0; nt < 4; ++nt)
      #pragma unroll
      for (int r = 0; r < 4; ++r) {
        int m = m0 + mt * 16 + quad * 4 + r;
        int n = n0 + nt * 16 + l15;
        float v = acc[mt][nt][r] + bias[n];
        u16 bv = f2bf(v);
        int b = m >> 11, p = m & 2047;
        int which = n / 768, hn = n % 768;
        int h = hn >> 6, d = hn & 63;
        if (which == 0)
          Q[((size_t)(b * H_ + h) * P_ + p) * HD_ + d] = bv;
        else if (which == 1)
          Km[((size_t)(b * H_ + h) * P_ + p) * HD_ + d] = bv;
        else
          Vt[((size_t)(b * H_ + h) * HD_ + d) * P_ + p] = bv;
      }
}

// ---------------- FC1 GEMM + exact GELU -> bf16 (8192,3072) ----------------
__global__ __launch_bounds__(256) void gemm_fc1_k(const u16* __restrict__ A,
                                                  const u16* __restrict__ wT,
                                                  const float* __restrict__ bias,
                                                  u16* __restrict__ out) {
  int wave = threadIdx.x >> 6;
  int m0 = blockIdx.y * 128 + (wave & 1) * 64;
  int n0 = blockIdx.x * 128 + (wave >> 1) * 64;
  f4 acc[4][4];
  ZERO44(acc);
  wave_gemm<768>(A + (size_t)m0 * 768, 768, wT + (size_t)n0 * 768, 768, acc);
  int lane = threadIdx.x & 63, l15 = lane & 15, quad = lane >> 4;
  #pragma unroll
  for (int mt = 0; mt < 4; ++mt)
    #pragma unroll
    for (int nt = 0; nt < 4; ++nt)
      #pragma unroll
      for (int r = 0; r < 4; ++r) {
        int m = m0 + mt * 16 + quad * 4 + r;
        int n = n0 + nt * 16 + l15;
        float v = acc[mt][nt][r] + bias[n];
        v = 0.5f * v * (1.f + erff(v * 0.70710678f));
        out[(size_t)m * 3072 + n] = f2bf(v);
      }
}

// ---------------- FC2 GEMM + bias + residual -> fp32 out ----------------
__global__ __launch_bounds__(256) void gemm_fc2_k(const u16* __restrict__ A,
                                                  const u16* __restrict__ wT,
                                                  const float* __restrict__ bias,
                                                  const float* __restrict__ resid,
                                                  float* __restrict__ out) {
  int wave = threadIdx.x >> 6;
  int m0 = blockIdx.y * 128 + (wave & 1) * 64;
  int n0 = blockIdx.x * 128 + (wave >> 1) * 64;
  f4 acc[4][4];
  ZERO44(acc);
  wave_gemm<3072>(A + (size_t)m0 * 3072, 3072, wT + (size_t)n0 * 3072, 3072, acc);
  int lane = threadIdx.x & 63, l15 = lane & 15, quad = lane >> 4;
  #pragma unroll
  for (int mt = 0; mt < 4; ++mt)
    #pragma unroll
    for (int nt = 0; nt < 4; ++nt)
      #pragma unroll
      for (int r = 0; r < 4; ++r) {
        int m = m0 + mt * 16 + quad * 4 + r;
        int n = n0 + nt * 16 + l15;
        size_t idx = (size_t)m * 768 + n;
        out[idx] = acc[mt][nt][r] + bias[n] + resid[idx];
      }
}

// ---------------- attention pass 1: recip[b][p][q] = 1/sum_h exp(s*scale), bf16 ----------------
// Computes S^T tiles (a=K rows q, b=Q rows p) so lane f4 = 4 consecutive q -> packed writes.
__global__ __launch_bounds__(256, 4) void attn_denom_k(const u16* __restrict__ Q,
                                                       const u16* __restrict__ Km,
                                                       u16* __restrict__ recip) {
  int pt = blockIdx.x, qt = blockIdx.y, b = blockIdx.z;
  int wave = threadIdx.x >> 6, lane = threadIdx.x & 63, l15 = lane & 15, quad = lane >> 4;
  __shared__ __align__(16) u16 red[4][64][72];  // 36.9 KB, padded stride (144B) vs bank wrap
  f4 esum[4][4];
  ZERO44(esum);
  for (int h = wave; h < H_; h += 4) {
    const u16* Kp = Km + ((size_t)(b * H_ + h) * P_ + qt * 64) * HD_;
    const u16* Qp = Q + ((size_t)(b * H_ + h) * P_ + pt * 64) * HD_;
    #pragma unroll
    for (int mt = 0; mt < 4; ++mt) {
      f4 s[4];
      #pragma unroll
      for (int nt = 0; nt < 4; ++nt) s[nt] = f4{0.f, 0.f, 0.f, 0.f};
      #pragma unroll
      for (int ks = 0; ks < 2; ++ks) {
        bf8 kf = *reinterpret_cast<const bf8*>(Kp + (size_t)(mt * 16 + l15) * 64 + ks * 32 + quad * 8);
        #pragma unroll
        for (int nt = 0; nt < 4; ++nt) {
          bf8 qfv = *reinterpret_cast<const bf8*>(Qp + (size_t)(nt * 16 + l15) * 64 + ks * 32 + quad * 8);
          s[nt] = mfma16(kf, qfv, s[nt]);
        }
      }
      #pragma unroll
      for (int nt = 0; nt < 4; ++nt)
        #pragma unroll
        for (int r = 0; r < 4; ++r)
          esum[mt][nt][r] += __builtin_amdgcn_exp2f(s[nt][r] * EXPC_);
    }
  }
  // lane value (mt,nt,r): q_loc = mt*16+quad*4+r, p_loc = nt*16+l15
  #pragma unroll
  for (int mt = 0; mt < 4; ++mt)
    #pragma unroll
    for (int nt = 0; nt < 4; ++nt)
      *reinterpret_cast<uint2*>(&red[wave][nt * 16 + l15][mt * 16 + quad * 4]) = pack4(esum[mt][nt]);
  __syncthreads();
  int p = threadIdx.x >> 2, ch = threadIdx.x & 3;
  size_t base = ((size_t)(b * P_ + pt * 64 + p)) * P_ + qt * 64;
  #pragma unroll
  for (int j = 0; j < 4; ++j) {
    int qb = ch * 16 + j * 4;
    f4 ssum = unpack4(*reinterpret_cast<const ushort4*>(&red[0][p][qb]));
    #pragma unroll
    for (int w = 1; w < 4; ++w)
      ssum += unpack4(*reinterpret_cast<const ushort4*>(&red[w][p][qb]));
    f4 rc;
    #pragma unroll
    for (int c = 0; c < 4; ++c) rc[c] = __builtin_amdgcn_rcpf(ssum[c]);
    *reinterpret_cast<uint2*>(recip + base + qb) = pack4(rc);
  }
}

// ---------------- attention pass 2: O = (exp(S*scale)*recip) @ V, + residual -> x2 ----------------
// S^T tiles (q-major f4) -> packed bf16 LDS A-tile [p][72]; O^T = mfma(a=Vt rows d, b=A rows p)
// so the O tile packs along d for the bf16 cross-wave reduction in the same LDS buffer.
__global__ __launch_bounds__(256, 4) void attn_out_k(const u16* __restrict__ Q,
                                                     const u16* __restrict__ Km,
                                                     const u16* __restrict__ Vt,
                                                     const u16* __restrict__ recip,
                                                     const float* __restrict__ xin,
                                                     float* __restrict__ x2) {
  int pt = blockIdx.x, h = blockIdx.y, b = blockIdx.z;
  int wave = threadIdx.x >> 6, lane = threadIdx.x & 63, l15 = lane & 15, quad = lane >> 4;
  __shared__ __align__(16) u16 smem[4][64][72];  // 36.9 KB: per-wave A-tile, reused for O reduce
  u16(*albuf)[72] = smem[wave];

  const u16* Qp = Q + ((size_t)(b * H_ + h) * P_ + pt * 64) * HD_;
  const u16* Kbase = Km + (size_t)(b * H_ + h) * P_ * HD_;
  const u16* Vbase = Vt + (size_t)(b * H_ + h) * HD_ * P_;
  const u16* rbase = recip + ((size_t)(b * P_) + pt * 64) * P_;

  f4 oacc[4][4];
  ZERO44(oacc);

  for (int qt = wave; qt < P_ / 64; qt += 4) {
    const u16* Kp = Kbase + (size_t)qt * 64 * HD_;
    // S^T compute + exp*recip -> albuf, one mt-row at a time (keeps s lifetime short)
    #pragma unroll
    for (int mt = 0; mt < 4; ++mt) {
      f4 s[4];
      #pragma unroll
      for (int nt = 0; nt < 4; ++nt) s[nt] = f4{0.f, 0.f, 0.f, 0.f};
      #pragma unroll
      for (int ks = 0; ks < 2; ++ks) {
        bf8 kf = *reinterpret_cast<const bf8*>(Kp + (size_t)(mt * 16 + l15) * 64 + ks * 32 + quad * 8);
        #pragma unroll
        for (int nt = 0; nt < 4; ++nt) {
          bf8 qfv = *reinterpret_cast<const bf8*>(Qp + (size_t)(nt * 16 + l15) * 64 + ks * 32 + quad * 8);
          s[nt] = mfma16(kf, qfv, s[nt]);
        }
      }
      #pragma unroll
      for (int nt = 0; nt < 4; ++nt) {
        ushort4 rv = *reinterpret_cast<const ushort4*>(rbase + (size_t)(nt * 16 + l15) * P_ +
                                                       qt * 64 + mt * 16 + quad * 4);
        f4 a;
        a[0] = __builtin_amdgcn_exp2f(s[nt][0] * EXPC_) * bf2f(rv.x);
        a[1] = __builtin_amdgcn_exp2f(s[nt][1] * EXPC_) * bf2f(rv.y);
        a[2] = __builtin_amdgcn_exp2f(s[nt][2] * EXPC_) * bf2f(rv.z);
        a[3] = __builtin_amdgcn_exp2f(s[nt][3] * EXPC_) * bf2f(rv.w);
        *reinterpret_cast<uint2*>(&albuf[nt * 16 + l15][mt * 16 + quad * 4]) = pack4(a);
      }
    }
    // O^T += Vt-frag * A-frag
    #pragma unroll
    for (int ks = 0; ks < 2; ++ks) {
      bf8 af[4];
      #pragma unroll
      for (int pi = 0; pi < 4; ++pi)
        af[pi] = *reinterpret_cast<const bf8*>(&albuf[pi * 16 + l15][ks * 32 + quad * 8]);
      #pragma unroll
      for (int dt = 0; dt < 4; ++dt) {
        bf8 vf = *reinterpret_cast<const bf8*>(Vbase + (size_t)(dt * 16 + l15) * P_ +
                                               qt * 64 + ks * 32 + quad * 8);
        #pragma unroll
        for (int pi = 0; pi < 4; ++pi)
          oacc[dt][pi] = mfma16(vf, af[pi], oacc[dt][pi]);
      }
    }
  }
  // write own O^T partial (bf16) into own smem region: value (dt,pi,r): d=dt*16+quad*4+r, p=pi*16+l15
  #pragma unroll
  for (int dt = 0; dt < 4; ++dt)
    #pragma unroll
    for (int pi = 0; pi < 4; ++pi)
      *reinterpret_cast<uint2*>(&smem[wave][pi * 16 + l15][dt * 16 + quad * 4]) = pack4(oacc[dt][pi]);
  __syncthreads();
  int p = threadIdx.x >> 2, ch = threadIdx.x & 3;
  size_t go = ((size_t)(b * P_) + pt * 64 + p) * D_ + h * 64;
  #pragma unroll
  for (int j = 0; j < 4; ++j) {
    int db = ch * 16 + j * 4;
    f4 o = unpack4(*reinterpret_cast<const ushort4*>(&smem[0][p][db]));
    #pragma unroll
    for (int w = 1; w < 4; ++w)
      o += unpack4(*reinterpret_cast<const ushort4*>(&smem[w][p][db]));
    f4 xv = *reinterpret_cast<const f4*>(xin + go + db);
    *reinterpret_cast<f4*>(x2 + go + db) = o + xv;
  }
}

extern "C" void kernel_launch(void* const* d_in, const int* in_sizes, int n_in,
                              void* d_out, int out_size, void* d_ws, size_t ws_size,
                              hipStream_t stream) {
  const float* x = (const float*)d_in[0];
  const float* ln1w = (const float*)d_in[1];
  const float* ln1b = (const float*)d_in[2];
  const float* wqkv = (const float*)d_in[3];
  const float* bqkv = (const float*)d_in[4];
  const float* ln2w = (const float*)d_in[5];
  const float* ln2b = (const float*)d_in[6];
  const float* wfc1 = (const float*)d_in[7];
  const float* bfc1 = (const float*)d_in[8];
  const float* wfc2 = (const float*)d_in[9];
  const float* bfc2 = (const float*)d_in[10];
  float* out = (float*)d_out;

  char* ws = (char*)d_ws;
  size_t off = 0;
  auto alloc = [&](size_t bytes) -> void* {
    void* p = ws + off;
    off += (bytes + 255) & ~(size_t)255;
    return p;
  };
  u16* hln = (u16*)alloc((size_t)8192 * 768 * 2);       // reused as hln2
  u16* wqkvT = (u16*)alloc((size_t)2304 * 768 * 2);
  u16* wfc1T = (u16*)alloc((size_t)3072 * 768 * 2);
  u16* wfc2T = (u16*)alloc((size_t)768 * 3072 * 2);
  u16* Qb = (u16*)alloc((size_t)B_ * H_ * P_ * HD_ * 2);
  u16* Kb = (u16*)alloc((size_t)B_ * H_ * P_ * HD_ * 2);
  u16* Vtb = (u16*)alloc((size_t)B_ * H_ * HD_ * P_ * 2);
  float* x2 = (float*)alloc((size_t)8192 * 768 * 4);
  // 64MB slot: recip (bf16, 32MB) first, then reused as fc1 output g (50MB)
  u16* recip = (u16*)alloc((size_t)B_ * P_ * P_ * 4);
  u16* g = recip;

  tcast_k<<<dim3(72, 24), 256, 0, stream>>>(wqkv, wqkvT, 768, 2304);
  tcast_k<<<dim3(96, 24), 256, 0, stream>>>(wfc1, wfc1T, 768, 3072);
  tcast_k<<<dim3(24, 96), 256, 0, stream>>>(wfc2, wfc2T, 3072, 768);
  ln_k<<<8192, 256, 0, stream>>>(x, ln1w, ln1b, hln);
  gemm_qkv_k<<<dim3(18, 64), 256, 0, stream>>>(hln, wqkvT, bqkv, Qb, Kb, Vtb);
  attn_denom_k<<<dim3(32, 32, 4), 256, 0, stream>>>(Qb, Kb, recip);
  attn_out_k<<<dim3(32, 12, 4), 256, 0, stream>>>(Qb, Kb, Vtb, recip, x, x2);
  ln_k<<<8192, 256, 0, stream>>>(x2, ln2w, ln2b, hln);
  gemm_fc1_k<<<dim3(24, 64), 256, 0, stream>>>(hln, wfc1T, bfc1, g);
  gemm_fc2_k<<<dim3(6, 64), 256, 0, stream>>>(g, wfc2T, bfc2, x2, out);
}

// Round 3
// 872.556 us; speedup vs baseline: 1.1314x; 1.1314x over previous
//
#include <hip/hip_runtime.h>
#include <hip/hip_bf16.h>

typedef __bf16 bf8 __attribute__((ext_vector_type(8)));
typedef float f4 __attribute__((ext_vector_type(4)));
typedef unsigned short u16;
typedef unsigned int u32;

#define B_ 4
#define P_ 2048
#define D_ 768
#define H_ 12
#define HD_ 64
// scale * log2(e): exp(s*0.125) = exp2(s * 0.18033688)
#define EXPC_ 0.18033688011112042f

__device__ __forceinline__ u16 f2bf(float f) {  // RNE, for GEMM/LN outputs
  union { float f; u32 u; } c; c.f = f;
  u32 u = c.u;
  u += 0x7fffu + ((u >> 16) & 1u);
  return (u16)(u >> 16);
}

__device__ __forceinline__ float bf2f(u16 v) {
  union { u32 u; float f; } c; c.u = (u32)v << 16; return c.f;
}

// truncating pack of 4 floats -> 4 bf16 in a uint2 (cheap: shift/and/or)
__device__ __forceinline__ uint2 pack4(f4 v) {
  union { float f; u32 u; } a, b, c, d;
  a.f = v[0]; b.f = v[1]; c.f = v[2]; d.f = v[3];
  uint2 r;
  r.x = (a.u >> 16) | (b.u & 0xffff0000u);
  r.y = (c.u >> 16) | (d.u & 0xffff0000u);
  return r;
}

__device__ __forceinline__ f4 unpack4(ushort4 v) {
  f4 r;
  r[0] = bf2f(v.x); r[1] = bf2f(v.y); r[2] = bf2f(v.z); r[3] = bf2f(v.w);
  return r;
}

__device__ __forceinline__ f4 mfma16(bf8 a, bf8 b, f4 c) {
  return __builtin_amdgcn_mfma_f32_16x16x32_bf16(a, b, c, 0, 0, 0);
}

#define ZERO44(acc)                    \
  {                                    \
    f4 z_ = {0.f, 0.f, 0.f, 0.f};      \
    for (int i_ = 0; i_ < 4; ++i_)     \
      for (int j_ = 0; j_ < 4; ++j_)   \
        acc[i_][j_] = z_;              \
  }

// ---------------- transpose-cast fp32 (R,C) -> bf16 (C,R) ----------------
__global__ __launch_bounds__(256) void tcast_k(const float* __restrict__ src,
                                               u16* __restrict__ dst, int R, int C) {
  __shared__ float t[32][33];
  int c0 = blockIdx.x * 32, r0 = blockIdx.y * 32;
  int tx = threadIdx.x & 31, ty = threadIdx.x >> 5;  // 32 x 8
  #pragma unroll
  for (int i = 0; i < 32; i += 8) {
    int r = r0 + ty + i, c = c0 + tx;
    t[ty + i][tx] = (r < R && c < C) ? src[(size_t)r * C + c] : 0.f;
  }
  __syncthreads();
  #pragma unroll
  for (int i = 0; i < 32; i += 8) {
    int c = c0 + ty + i, r = r0 + tx;
    if (c < C && r < R) dst[(size_t)c * R + r] = f2bf(t[tx][ty + i]);
  }
}

// ---------------- layernorm fp32 -> bf16, one row (768) per block ----------------
__global__ __launch_bounds__(256) void ln_k(const float* __restrict__ x,
                                            const float* __restrict__ g,
                                            const float* __restrict__ b,
                                            u16* __restrict__ out) {
  int row = blockIdx.x;
  const float* xr = x + (size_t)row * D_;
  float v0 = xr[threadIdx.x], v1 = xr[threadIdx.x + 256], v2 = xr[threadIdx.x + 512];
  float s = v0 + v1 + v2;
  float s2 = v0 * v0 + v1 * v1 + v2 * v2;
  #pragma unroll
  for (int o = 32; o > 0; o >>= 1) {
    s += __shfl_down(s, o, 64);
    s2 += __shfl_down(s2, o, 64);
  }
  __shared__ float a[4], a2[4];
  int wv = threadIdx.x >> 6;
  if ((threadIdx.x & 63) == 0) { a[wv] = s; a2[wv] = s2; }
  __syncthreads();
  s = a[0] + a[1] + a[2] + a[3];
  s2 = a2[0] + a2[1] + a2[2] + a2[3];
  float mean = s * (1.f / 768.f);
  float var = s2 * (1.f / 768.f) - mean * mean;
  float rstd = rsqrtf(var + 1e-5f);
  u16* orow = out + (size_t)row * D_;
  float vv[3] = {v0, v1, v2};
  #pragma unroll
  for (int j = 0; j < 3; ++j) {
    int i = threadIdx.x + j * 256;
    orow[i] = f2bf((vv[j] - mean) * rstd * g[i] + b[i]);
  }
}

// ---------------- wave-level 64x64 GEMM core: C += A(M,K) * Bt(N,K)^T ----------------
template <int K>
__device__ __forceinline__ void wave_gemm(const u16* __restrict__ A, int lda,
                                          const u16* __restrict__ Bt, int ldb,
                                          f4 acc[4][4]) {
  const int lane = threadIdx.x & 63, l15 = lane & 15, quad = lane >> 4;
  #pragma unroll 2
  for (int k = 0; k < K; k += 32) {
    bf8 a[4], b[4];
    #pragma unroll
    for (int mt = 0; mt < 4; ++mt)
      a[mt] = *reinterpret_cast<const bf8*>(A + (size_t)(mt * 16 + l15) * lda + k + quad * 8);
    #pragma unroll
    for (int nt = 0; nt < 4; ++nt)
      b[nt] = *reinterpret_cast<const bf8*>(Bt + (size_t)(nt * 16 + l15) * ldb + k + quad * 8);
    #pragma unroll
    for (int mt = 0; mt < 4; ++mt)
      #pragma unroll
      for (int nt = 0; nt < 4; ++nt)
        acc[mt][nt] = mfma16(a[mt], b[nt], acc[mt][nt]);
  }
}

// ---------------- QKV GEMM: hln(8192,768) @ wT(2304,768)^T + bias -> Q,K,(V^T) bf16 ----------------
__global__ __launch_bounds__(256) void gemm_qkv_k(const u16* __restrict__ hln,
                                                  const u16* __restrict__ wT,
                                                  const float* __restrict__ bias,
                                                  u16* __restrict__ Q, u16* __restrict__ Km,
                                                  u16* __restrict__ Vt) {
  int wave = threadIdx.x >> 6;
  int m0 = blockIdx.y * 128 + (wave & 1) * 64;
  int n0 = blockIdx.x * 128 + (wave >> 1) * 64;
  f4 acc[4][4];
  ZERO44(acc);
  wave_gemm<768>(hln + (size_t)m0 * 768, 768, wT + (size_t)n0 * 768, 768, acc);
  int lane = threadIdx.x & 63, l15 = lane & 15, quad = lane >> 4;
  #pragma unroll
  for (int mt = 0; mt < 4; ++mt)
    #pragma unroll
    for (int nt = 0; nt < 4; ++nt)
      #pragma unroll
      for (int r = 0; r < 4; ++r) {
        int m = m0 + mt * 16 + quad * 4 + r;
        int n = n0 + nt * 16 + l15;
        float v = acc[mt][nt][r] + bias[n];
        u16 bv = f2bf(v);
        int b = m >> 11, p = m & 2047;
        int which = n / 768, hn = n % 768;
        int h = hn >> 6, d = hn & 63;
        if (which == 0)
          Q[((size_t)(b * H_ + h) * P_ + p) * HD_ + d] = bv;
        else if (which == 1)
          Km[((size_t)(b * H_ + h) * P_ + p) * HD_ + d] = bv;
        else
          Vt[((size_t)(b * H_ + h) * HD_ + d) * P_ + p] = bv;
      }
}

// ---------------- FC1 GEMM + exact GELU -> bf16 (8192,3072) ----------------
__global__ __launch_bounds__(256) void gemm_fc1_k(const u16* __restrict__ A,
                                                  const u16* __restrict__ wT,
                                                  const float* __restrict__ bias,
                                                  u16* __restrict__ out) {
  int wave = threadIdx.x >> 6;
  int m0 = blockIdx.y * 128 + (wave & 1) * 64;
  int n0 = blockIdx.x * 128 + (wave >> 1) * 64;
  f4 acc[4][4];
  ZERO44(acc);
  wave_gemm<768>(A + (size_t)m0 * 768, 768, wT + (size_t)n0 * 768, 768, acc);
  int lane = threadIdx.x & 63, l15 = lane & 15, quad = lane >> 4;
  #pragma unroll
  for (int mt = 0; mt < 4; ++mt)
    #pragma unroll
    for (int nt = 0; nt < 4; ++nt)
      #pragma unroll
      for (int r = 0; r < 4; ++r) {
        int m = m0 + mt * 16 + quad * 4 + r;
        int n = n0 + nt * 16 + l15;
        float v = acc[mt][nt][r] + bias[n];
        v = 0.5f * v * (1.f + erff(v * 0.70710678f));
        out[(size_t)m * 3072 + n] = f2bf(v);
      }
}

// ---------------- FC2 GEMM + bias + residual -> fp32 out ----------------
__global__ __launch_bounds__(256) void gemm_fc2_k(const u16* __restrict__ A,
                                                  const u16* __restrict__ wT,
                                                  const float* __restrict__ bias,
                                                  const float* __restrict__ resid,
                                                  float* __restrict__ out) {
  int wave = threadIdx.x >> 6;
  int m0 = blockIdx.y * 128 + (wave & 1) * 64;
  int n0 = blockIdx.x * 128 + (wave >> 1) * 64;
  f4 acc[4][4];
  ZERO44(acc);
  wave_gemm<3072>(A + (size_t)m0 * 3072, 3072, wT + (size_t)n0 * 3072, 3072, acc);
  int lane = threadIdx.x & 63, l15 = lane & 15, quad = lane >> 4;
  #pragma unroll
  for (int mt = 0; mt < 4; ++mt)
    #pragma unroll
    for (int nt = 0; nt < 4; ++nt)
      #pragma unroll
      for (int r = 0; r < 4; ++r) {
        int m = m0 + mt * 16 + quad * 4 + r;
        int n = n0 + nt * 16 + l15;
        size_t idx = (size_t)m * 768 + n;
        out[idx] = acc[mt][nt][r] + bias[n] + resid[idx];
      }
}

// ---------------- attention pass 1: recip[b][p][q] = 1/sum_h exp(s*scale), bf16 ----------------
// Computes S^T tiles (a=K rows q, b=Q rows p) so lane f4 = 4 consecutive q -> packed writes.
__global__ __launch_bounds__(256) void attn_denom_k(const u16* __restrict__ Q,
                                                    const u16* __restrict__ Km,
                                                    u16* __restrict__ recip) {
  int pt = blockIdx.x, qt = blockIdx.y, b = blockIdx.z;
  int wave = threadIdx.x >> 6, lane = threadIdx.x & 63, l15 = lane & 15, quad = lane >> 4;
  __shared__ __align__(16) u16 red[4][64][72];  // 36.9 KB, padded stride (144B) vs bank wrap
  f4 esum[4][4];
  ZERO44(esum);
  for (int h = wave; h < H_; h += 4) {
    const u16* Kp = Km + ((size_t)(b * H_ + h) * P_ + qt * 64) * HD_;
    const u16* Qp = Q + ((size_t)(b * H_ + h) * P_ + pt * 64) * HD_;
    #pragma unroll
    for (int mt = 0; mt < 4; ++mt) {
      f4 s[4];
      #pragma unroll
      for (int nt = 0; nt < 4; ++nt) s[nt] = f4{0.f, 0.f, 0.f, 0.f};
      #pragma unroll
      for (int ks = 0; ks < 2; ++ks) {
        bf8 kf = *reinterpret_cast<const bf8*>(Kp + (size_t)(mt * 16 + l15) * 64 + ks * 32 + quad * 8);
        #pragma unroll
        for (int nt = 0; nt < 4; ++nt) {
          bf8 qfv = *reinterpret_cast<const bf8*>(Qp + (size_t)(nt * 16 + l15) * 64 + ks * 32 + quad * 8);
          s[nt] = mfma16(kf, qfv, s[nt]);
        }
      }
      #pragma unroll
      for (int nt = 0; nt < 4; ++nt)
        #pragma unroll
        for (int r = 0; r < 4; ++r)
          esum[mt][nt][r] += __builtin_amdgcn_exp2f(s[nt][r] * EXPC_);
    }
  }
  // lane value (mt,nt,r): q_loc = mt*16+quad*4+r, p_loc = nt*16+l15
  #pragma unroll
  for (int mt = 0; mt < 4; ++mt)
    #pragma unroll
    for (int nt = 0; nt < 4; ++nt)
      *reinterpret_cast<uint2*>(&red[wave][nt * 16 + l15][mt * 16 + quad * 4]) = pack4(esum[mt][nt]);
  __syncthreads();
  int p = threadIdx.x >> 2, ch = threadIdx.x & 3;
  size_t base = ((size_t)(b * P_ + pt * 64 + p)) * P_ + qt * 64;
  #pragma unroll
  for (int j = 0; j < 4; ++j) {
    int qb = ch * 16 + j * 4;
    f4 ssum = unpack4(*reinterpret_cast<const ushort4*>(&red[0][p][qb]));
    #pragma unroll
    for (int w = 1; w < 4; ++w)
      ssum += unpack4(*reinterpret_cast<const ushort4*>(&red[w][p][qb]));
    f4 rc;
    #pragma unroll
    for (int c = 0; c < 4; ++c) rc[c] = __builtin_amdgcn_rcpf(ssum[c]);
    *reinterpret_cast<uint2*>(recip + base + qb) = pack4(rc);
  }
}

// ---------------- attention pass 2: O = (exp(S*scale)*recip) @ V, + residual -> x2 ----------------
// S^T tiles (q-major f4) -> packed bf16 LDS A-tile [p][72]; O^T = mfma(a=Vt rows d, b=A rows p)
// so the O tile packs along d for the bf16 cross-wave reduction in the same LDS buffer.
__global__ __launch_bounds__(256) void attn_out_k(const u16* __restrict__ Q,
                                                  const u16* __restrict__ Km,
                                                  const u16* __restrict__ Vt,
                                                  const u16* __restrict__ recip,
                                                  const float* __restrict__ xin,
                                                  float* __restrict__ x2) {
  int pt = blockIdx.x, h = blockIdx.y, b = blockIdx.z;
  int wave = threadIdx.x >> 6, lane = threadIdx.x & 63, l15 = lane & 15, quad = lane >> 4;
  __shared__ __align__(16) u16 smem[4][64][72];  // 36.9 KB: per-wave A-tile, reused for O reduce
  u16(*albuf)[72] = smem[wave];

  const u16* Qp = Q + ((size_t)(b * H_ + h) * P_ + pt * 64) * HD_;
  const u16* Kbase = Km + (size_t)(b * H_ + h) * P_ * HD_;
  const u16* Vbase = Vt + (size_t)(b * H_ + h) * HD_ * P_;
  const u16* rbase = recip + ((size_t)(b * P_) + pt * 64) * P_;

  // preload Q fragments for this block's 64 p-rows (reused across all qt tiles)
  bf8 qf[4][2];
  #pragma unroll
  for (int nt = 0; nt < 4; ++nt)
    #pragma unroll
    for (int ks = 0; ks < 2; ++ks)
      qf[nt][ks] = *reinterpret_cast<const bf8*>(Qp + (size_t)(nt * 16 + l15) * 64 + ks * 32 + quad * 8);

  f4 oacc[4][4];
  ZERO44(oacc);

  for (int qt = wave; qt < P_ / 64; qt += 4) {
    const u16* Kp = Kbase + (size_t)qt * 64 * HD_;
    // S^T compute + exp*recip -> albuf, one mt-row at a time (keeps s lifetime short)
    #pragma unroll
    for (int mt = 0; mt < 4; ++mt) {
      f4 s[4];
      #pragma unroll
      for (int nt = 0; nt < 4; ++nt) s[nt] = f4{0.f, 0.f, 0.f, 0.f};
      #pragma unroll
      for (int ks = 0; ks < 2; ++ks) {
        bf8 kf = *reinterpret_cast<const bf8*>(Kp + (size_t)(mt * 16 + l15) * 64 + ks * 32 + quad * 8);
        #pragma unroll
        for (int nt = 0; nt < 4; ++nt)
          s[nt] = mfma16(kf, qf[nt][ks], s[nt]);
      }
      #pragma unroll
      for (int nt = 0; nt < 4; ++nt) {
        ushort4 rv = *reinterpret_cast<const ushort4*>(rbase + (size_t)(nt * 16 + l15) * P_ +
                                                       qt * 64 + mt * 16 + quad * 4);
        f4 a;
        a[0] = __builtin_amdgcn_exp2f(s[nt][0] * EXPC_) * bf2f(rv.x);
        a[1] = __builtin_amdgcn_exp2f(s[nt][1] * EXPC_) * bf2f(rv.y);
        a[2] = __builtin_amdgcn_exp2f(s[nt][2] * EXPC_) * bf2f(rv.z);
        a[3] = __builtin_amdgcn_exp2f(s[nt][3] * EXPC_) * bf2f(rv.w);
        *reinterpret_cast<uint2*>(&albuf[nt * 16 + l15][mt * 16 + quad * 4]) = pack4(a);
      }
    }
    // O^T += Vt-frag * A-frag
    #pragma unroll
    for (int ks = 0; ks < 2; ++ks) {
      bf8 af[4];
      #pragma unroll
      for (int pi = 0; pi < 4; ++pi)
        af[pi] = *reinterpret_cast<const bf8*>(&albuf[pi * 16 + l15][ks * 32 + quad * 8]);
      #pragma unroll
      for (int dt = 0; dt < 4; ++dt) {
        bf8 vf = *reinterpret_cast<const bf8*>(Vbase + (size_t)(dt * 16 + l15) * P_ +
                                               qt * 64 + ks * 32 + quad * 8);
        #pragma unroll
        for (int pi = 0; pi < 4; ++pi)
          oacc[dt][pi] = mfma16(vf, af[pi], oacc[dt][pi]);
      }
    }
  }
  // write own O^T partial (bf16) into own smem region: value (dt,pi,r): d=dt*16+quad*4+r, p=pi*16+l15
  #pragma unroll
  for (int dt = 0; dt < 4; ++dt)
    #pragma unroll
    for (int pi = 0; pi < 4; ++pi)
      *reinterpret_cast<uint2*>(&smem[wave][pi * 16 + l15][dt * 16 + quad * 4]) = pack4(oacc[dt][pi]);
  __syncthreads();
  int p = threadIdx.x >> 2, ch = threadIdx.x & 3;
  size_t go = ((size_t)(b * P_) + pt * 64 + p) * D_ + h * 64;
  #pragma unroll
  for (int j = 0; j < 4; ++j) {
    int db = ch * 16 + j * 4;
    f4 o = unpack4(*reinterpret_cast<const ushort4*>(&smem[0][p][db]));
    #pragma unroll
    for (int w = 1; w < 4; ++w)
      o += unpack4(*reinterpret_cast<const ushort4*>(&smem[w][p][db]));
    f4 xv = *reinterpret_cast<const f4*>(xin + go + db);
    *reinterpret_cast<f4*>(x2 + go + db) = o + xv;
  }
}

extern "C" void kernel_launch(void* const* d_in, const int* in_sizes, int n_in,
                              void* d_out, int out_size, void* d_ws, size_t ws_size,
                              hipStream_t stream) {
  const float* x = (const float*)d_in[0];
  const float* ln1w = (const float*)d_in[1];
  const float* ln1b = (const float*)d_in[2];
  const float* wqkv = (const float*)d_in[3];
  const float* bqkv = (const float*)d_in[4];
  const float* ln2w = (const float*)d_in[5];
  const float* ln2b = (const float*)d_in[6];
  const float* wfc1 = (const float*)d_in[7];
  const float* bfc1 = (const float*)d_in[8];
  const float* wfc2 = (const float*)d_in[9];
  const float* bfc2 = (const float*)d_in[10];
  float* out = (float*)d_out;

  char* ws = (char*)d_ws;
  size_t off = 0;
  auto alloc = [&](size_t bytes) -> void* {
    void* p = ws + off;
    off += (bytes + 255) & ~(size_t)255;
    return p;
  };
  u16* hln = (u16*)alloc((size_t)8192 * 768 * 2);       // reused as hln2
  u16* wqkvT = (u16*)alloc((size_t)2304 * 768 * 2);
  u16* wfc1T = (u16*)alloc((size_t)3072 * 768 * 2);
  u16* wfc2T = (u16*)alloc((size_t)768 * 3072 * 2);
  u16* Qb = (u16*)alloc((size_t)B_ * H_ * P_ * HD_ * 2);
  u16* Kb = (u16*)alloc((size_t)B_ * H_ * P_ * HD_ * 2);
  u16* Vtb = (u16*)alloc((size_t)B_ * H_ * HD_ * P_ * 2);
  float* x2 = (float*)alloc((size_t)8192 * 768 * 4);
  // 64MB slot: recip (bf16, 32MB) first, then reused as fc1 output g (50MB)
  u16* recip = (u16*)alloc((size_t)B_ * P_ * P_ * 4);
  u16* g = recip;

  tcast_k<<<dim3(72, 24), 256, 0, stream>>>(wqkv, wqkvT, 768, 2304);
  tcast_k<<<dim3(96, 24), 256, 0, stream>>>(wfc1, wfc1T, 768, 3072);
  tcast_k<<<dim3(24, 96), 256, 0, stream>>>(wfc2, wfc2T, 3072, 768);
  ln_k<<<8192, 256, 0, stream>>>(x, ln1w, ln1b, hln);
  gemm_qkv_k<<<dim3(18, 64), 256, 0, stream>>>(hln, wqkvT, bqkv, Qb, Kb, Vtb);
  attn_denom_k<<<dim3(32, 32, 4), 256, 0, stream>>>(Qb, Kb, recip);
  attn_out_k<<<dim3(32, 12, 4), 256, 0, stream>>>(Qb, Kb, Vtb, recip, x, x2);
  ln_k<<<8192, 256, 0, stream>>>(x2, ln2w, ln2b, hln);
  gemm_fc1_k<<<dim3(24, 64), 256, 0, stream>>>(hln, wfc1T, bfc1, g);
  gemm_fc2_k<<<dim3(6, 64), 256, 0, stream>>>(g, wfc2T, bfc2, x2, out);
}

// Round 4
// 627.073 us; speedup vs baseline: 1.5743x; 1.3915x over previous
//
#include <hip/hip_runtime.h>
#include <hip/hip_bf16.h>

typedef __bf16 bf8 __attribute__((ext_vector_type(8)));
typedef float f4 __attribute__((ext_vector_type(4)));
typedef unsigned short u16;
typedef unsigned int u32;

#define B_ 4
#define P_ 2048
#define D_ 768
#define H_ 12
#define HD_ 64
// scale * log2(e): exp(s*0.125) = exp2(s * 0.18033688)
#define EXPC_ 0.18033688011112042f

typedef const __attribute__((address_space(1))) void gvoid;
typedef __attribute__((address_space(3))) void lvoid;

__device__ __forceinline__ void gl_lds16(const u16* g, u16* l) {
  __builtin_amdgcn_global_load_lds((gvoid*)g, (lvoid*)l, 16, 0, 0);
}

__device__ __forceinline__ u16 f2bf(float f) {  // RNE
  union { float f; u32 u; } c; c.f = f;
  u32 u = c.u;
  u += 0x7fffu + ((u >> 16) & 1u);
  return (u16)(u >> 16);
}

__device__ __forceinline__ float bf2f(u16 v) {
  union { u32 u; float f; } c; c.u = (u32)v << 16; return c.f;
}

__device__ __forceinline__ uint2 pack4(f4 v) {  // truncating 4xf32 -> 4xbf16
  union { float f; u32 u; } a, b, c, d;
  a.f = v[0]; b.f = v[1]; c.f = v[2]; d.f = v[3];
  uint2 r;
  r.x = (a.u >> 16) | (b.u & 0xffff0000u);
  r.y = (c.u >> 16) | (d.u & 0xffff0000u);
  return r;
}

__device__ __forceinline__ f4 unpack4(ushort4 v) {
  f4 r;
  r[0] = bf2f(v.x); r[1] = bf2f(v.y); r[2] = bf2f(v.z); r[3] = bf2f(v.w);
  return r;
}

__device__ __forceinline__ f4 mfma16(bf8 a, bf8 b, f4 c) {
  return __builtin_amdgcn_mfma_f32_16x16x32_bf16(a, b, c, 0, 0, 0);
}

#define ZERO44(acc)                    \
  {                                    \
    f4 z_ = {0.f, 0.f, 0.f, 0.f};      \
    for (int i_ = 0; i_ < 4; ++i_)     \
      for (int j_ = 0; j_ < 4; ++j_)   \
        acc[i_][j_] = z_;              \
  }

// ---------------- transpose-cast fp32 (R,C) -> bf16 (C,R) ----------------
__global__ __launch_bounds__(256) void tcast_k(const float* __restrict__ src,
                                               u16* __restrict__ dst, int R, int C) {
  __shared__ float t[32][33];
  int c0 = blockIdx.x * 32, r0 = blockIdx.y * 32;
  int tx = threadIdx.x & 31, ty = threadIdx.x >> 5;
  #pragma unroll
  for (int i = 0; i < 32; i += 8) {
    int r = r0 + ty + i, c = c0 + tx;
    t[ty + i][tx] = (r < R && c < C) ? src[(size_t)r * C + c] : 0.f;
  }
  __syncthreads();
  #pragma unroll
  for (int i = 0; i < 32; i += 8) {
    int c = c0 + ty + i, r = r0 + tx;
    if (c < C && r < R) dst[(size_t)c * R + r] = f2bf(t[tx][ty + i]);
  }
}

// ---------------- layernorm fp32 -> bf16 ----------------
__global__ __launch_bounds__(256) void ln_k(const float* __restrict__ x,
                                            const float* __restrict__ g,
                                            const float* __restrict__ b,
                                            u16* __restrict__ out) {
  int row = blockIdx.x;
  const float* xr = x + (size_t)row * D_;
  float v0 = xr[threadIdx.x], v1 = xr[threadIdx.x + 256], v2 = xr[threadIdx.x + 512];
  float s = v0 + v1 + v2;
  float s2 = v0 * v0 + v1 * v1 + v2 * v2;
  #pragma unroll
  for (int o = 32; o > 0; o >>= 1) {
    s += __shfl_down(s, o, 64);
    s2 += __shfl_down(s2, o, 64);
  }
  __shared__ float a[4], a2[4];
  int wv = threadIdx.x >> 6;
  if ((threadIdx.x & 63) == 0) { a[wv] = s; a2[wv] = s2; }
  __syncthreads();
  s = a[0] + a[1] + a[2] + a[3];
  s2 = a2[0] + a2[1] + a2[2] + a2[3];
  float mean = s * (1.f / 768.f);
  float var = s2 * (1.f / 768.f) - mean * mean;
  float rstd = rsqrtf(var + 1e-5f);
  u16* orow = out + (size_t)row * D_;
  float vv[3] = {v0, v1, v2};
  #pragma unroll
  for (int j = 0; j < 3; ++j) {
    int i = threadIdx.x + j * 256;
    orow[i] = f2bf((vv[j] - mean) * rstd * g[i] + b[i]);
  }
}

// ============ staged 128x128 GEMM core (m97 pattern), K-stride 32 ============
// A (M,K) row-major bf16, Bt (N,K) row-major bf16. Each wave computes 64x64.
// As/Bs: [128][32] u16, contiguous (global_load_lds requires unpadded layout).
template <int K>
__device__ __forceinline__ void staged_core(const u16* __restrict__ Ab,
                                            const u16* __restrict__ Bb,
                                            u16* As, u16* Bs, f4 acc[4][4]) {
  const int wave = threadIdx.x >> 6, lane = threadIdx.x & 63;
  const int l15 = lane & 15, quad = lane >> 4;
  const int lrow = lane >> 2;
  const int lcol = (lane & 3) * 8;
  const int mw = (wave & 1) * 64, nw = (wave >> 1) * 64;
  for (int k0 = 0; k0 < K; k0 += 32) {
    const u16* ga = Ab + (size_t)(wave * 32 + lrow) * K + k0 + lcol;
    gl_lds16(ga, &As[(wave * 32) * 32]);
    gl_lds16(ga + (size_t)16 * K, &As[(wave * 32 + 16) * 32]);
    const u16* gb = Bb + (size_t)(wave * 32 + lrow) * K + k0 + lcol;
    gl_lds16(gb, &Bs[(wave * 32) * 32]);
    gl_lds16(gb + (size_t)16 * K, &Bs[(wave * 32 + 16) * 32]);
    __syncthreads();
    bf8 a[4], b[4];
    #pragma unroll
    for (int mt = 0; mt < 4; ++mt)
      a[mt] = *reinterpret_cast<const bf8*>(&As[(mw + mt * 16 + l15) * 32 + quad * 8]);
    #pragma unroll
    for (int nt = 0; nt < 4; ++nt)
      b[nt] = *reinterpret_cast<const bf8*>(&Bs[(nw + nt * 16 + l15) * 32 + quad * 8]);
    #pragma unroll
    for (int mt = 0; mt < 4; ++mt)
      #pragma unroll
      for (int nt = 0; nt < 4; ++nt)
        acc[mt][nt] = mfma16(a[mt], b[nt], acc[mt][nt]);
    __syncthreads();
  }
}

// ---------------- QKV GEMM staged ----------------
__global__ __launch_bounds__(256) void gemm_qkv_k(const u16* __restrict__ hln,
                                                  const u16* __restrict__ wT,
                                                  const float* __restrict__ bias,
                                                  u16* __restrict__ Q, u16* __restrict__ Km,
                                                  u16* __restrict__ Vt) {
  __shared__ u16 As[128 * 32], Bs[128 * 32];
  int m0 = blockIdx.y * 128, n0 = blockIdx.x * 128;
  f4 acc[4][4];
  ZERO44(acc);
  staged_core<768>(hln + (size_t)m0 * 768, wT + (size_t)n0 * 768, As, Bs, acc);
  int wave = threadIdx.x >> 6, lane = threadIdx.x & 63, l15 = lane & 15, quad = lane >> 4;
  int mW = m0 + (wave & 1) * 64, nW = n0 + (wave >> 1) * 64;
  #pragma unroll
  for (int mt = 0; mt < 4; ++mt)
    #pragma unroll
    for (int nt = 0; nt < 4; ++nt)
      #pragma unroll
      for (int r = 0; r < 4; ++r) {
        int m = mW + mt * 16 + quad * 4 + r;
        int n = nW + nt * 16 + l15;
        float v = acc[mt][nt][r] + bias[n];
        u16 bv = f2bf(v);
        int b = m >> 11, p = m & 2047;
        int which = n / 768, hn = n % 768;
        int h = hn >> 6, d = hn & 63;
        if (which == 0)
          Q[((size_t)(b * H_ + h) * P_ + p) * HD_ + d] = bv;
        else if (which == 1)
          Km[((size_t)(b * H_ + h) * P_ + p) * HD_ + d] = bv;
        else
          Vt[((size_t)(b * H_ + h) * HD_ + d) * P_ + p] = bv;
      }
}

// ---------------- FC1 GEMM staged + exact GELU ----------------
__global__ __launch_bounds__(256) void gemm_fc1_k(const u16* __restrict__ A,
                                                  const u16* __restrict__ wT,
                                                  const float* __restrict__ bias,
                                                  u16* __restrict__ out) {
  __shared__ u16 As[128 * 32], Bs[128 * 32];
  int m0 = blockIdx.y * 128, n0 = blockIdx.x * 128;
  f4 acc[4][4];
  ZERO44(acc);
  staged_core<768>(A + (size_t)m0 * 768, wT + (size_t)n0 * 768, As, Bs, acc);
  int wave = threadIdx.x >> 6, lane = threadIdx.x & 63, l15 = lane & 15, quad = lane >> 4;
  int mW = m0 + (wave & 1) * 64, nW = n0 + (wave >> 1) * 64;
  #pragma unroll
  for (int mt = 0; mt < 4; ++mt)
    #pragma unroll
    for (int nt = 0; nt < 4; ++nt)
      #pragma unroll
      for (int r = 0; r < 4; ++r) {
        int m = mW + mt * 16 + quad * 4 + r;
        int n = nW + nt * 16 + l15;
        float v = acc[mt][nt][r] + bias[n];
        v = 0.5f * v * (1.f + erff(v * 0.70710678f));
        out[(size_t)m * 3072 + n] = f2bf(v);
      }
}

// ---------------- FC2 GEMM staged (BM=128, BN=64), +bias +residual -> fp32 ----------------
__global__ __launch_bounds__(256) void gemm_fc2_k(const u16* __restrict__ A,
                                                  const u16* __restrict__ wT,
                                                  const float* __restrict__ bias,
                                                  const float* __restrict__ resid,
                                                  float* __restrict__ out) {
  __shared__ u16 As[128 * 32], Bs[64 * 32];
  int wave = threadIdx.x >> 6, lane = threadIdx.x & 63, l15 = lane & 15, quad = lane >> 4;
  int lrow = lane >> 2, lcol = (lane & 3) * 8;
  int m0 = blockIdx.y * 128, n0 = blockIdx.x * 64;
  const u16* Ab = A + (size_t)m0 * 3072;
  const u16* Bb = wT + (size_t)n0 * 3072;
  int mw = (wave & 1) * 64, nw = (wave >> 1) * 32;
  f4 acc[4][2];
  #pragma unroll
  for (int i = 0; i < 4; ++i)
    #pragma unroll
    for (int j = 0; j < 2; ++j) acc[i][j] = f4{0.f, 0.f, 0.f, 0.f};
  for (int k0 = 0; k0 < 3072; k0 += 32) {
    const u16* ga = Ab + (size_t)(wave * 32 + lrow) * 3072 + k0 + lcol;
    gl_lds16(ga, &As[(wave * 32) * 32]);
    gl_lds16(ga + (size_t)16 * 3072, &As[(wave * 32 + 16) * 32]);
    const u16* gb = Bb + (size_t)(wave * 16 + lrow) * 3072 + k0 + lcol;
    gl_lds16(gb, &Bs[(wave * 16) * 32]);
    __syncthreads();
    bf8 a[4], b[2];
    #pragma unroll
    for (int mt = 0; mt < 4; ++mt)
      a[mt] = *reinterpret_cast<const bf8*>(&As[(mw + mt * 16 + l15) * 32 + quad * 8]);
    #pragma unroll
    for (int nt = 0; nt < 2; ++nt)
      b[nt] = *reinterpret_cast<const bf8*>(&Bs[(nw + nt * 16 + l15) * 32 + quad * 8]);
    #pragma unroll
    for (int mt = 0; mt < 4; ++mt)
      #pragma unroll
      for (int nt = 0; nt < 2; ++nt)
        acc[mt][nt] = mfma16(a[mt], b[nt], acc[mt][nt]);
    __syncthreads();
  }
  int mW = m0 + mw, nW = n0 + nw;
  #pragma unroll
  for (int mt = 0; mt < 4; ++mt)
    #pragma unroll
    for (int nt = 0; nt < 2; ++nt)
      #pragma unroll
      for (int r = 0; r < 4; ++r) {
        int m = mW + mt * 16 + quad * 4 + r;
        int n = nW + nt * 16 + l15;
        size_t idx = (size_t)m * 768 + n;
        out[idx] = acc[mt][nt][r] + bias[n] + resid[idx];
      }
}

// ---------------- attention pass 1: recip[b][p][q] = 1/sum_h exp(s*scale), bf16 ----------------
__global__ __launch_bounds__(256) void attn_denom_k(const u16* __restrict__ Q,
                                                    const u16* __restrict__ Km,
                                                    u16* __restrict__ recip) {
  int pt = blockIdx.x, qt = blockIdx.y, b = blockIdx.z;
  int wave = threadIdx.x >> 6, lane = threadIdx.x & 63, l15 = lane & 15, quad = lane >> 4;
  __shared__ __align__(16) u16 red[4][64][72];
  f4 esum[4][4];
  ZERO44(esum);
  for (int h = wave; h < H_; h += 4) {
    const u16* Kp = Km + ((size_t)(b * H_ + h) * P_ + qt * 64) * HD_;
    const u16* Qp = Q + ((size_t)(b * H_ + h) * P_ + pt * 64) * HD_;
    // hoisted fragment loads: 16 VMEM issued together
    bf8 kf[4][2], qf[4][2];
    #pragma unroll
    for (int i = 0; i < 4; ++i)
      #pragma unroll
      for (int ks = 0; ks < 2; ++ks) {
        kf[i][ks] = *reinterpret_cast<const bf8*>(Kp + (size_t)(i * 16 + l15) * 64 + ks * 32 + quad * 8);
        qf[i][ks] = *reinterpret_cast<const bf8*>(Qp + (size_t)(i * 16 + l15) * 64 + ks * 32 + quad * 8);
      }
    #pragma unroll
    for (int mt = 0; mt < 4; ++mt) {
      f4 s[4];
      #pragma unroll
      for (int nt = 0; nt < 4; ++nt) s[nt] = f4{0.f, 0.f, 0.f, 0.f};
      #pragma unroll
      for (int ks = 0; ks < 2; ++ks)
        #pragma unroll
        for (int nt = 0; nt < 4; ++nt)
          s[nt] = mfma16(kf[mt][ks], qf[nt][ks], s[nt]);
      #pragma unroll
      for (int nt = 0; nt < 4; ++nt)
        #pragma unroll
        for (int r = 0; r < 4; ++r)
          esum[mt][nt][r] += __builtin_amdgcn_exp2f(s[nt][r] * EXPC_);
    }
  }
  #pragma unroll
  for (int mt = 0; mt < 4; ++mt)
    #pragma unroll
    for (int nt = 0; nt < 4; ++nt)
      *reinterpret_cast<uint2*>(&red[wave][nt * 16 + l15][mt * 16 + quad * 4]) = pack4(esum[mt][nt]);
  __syncthreads();
  int p = threadIdx.x >> 2, ch = threadIdx.x & 3;
  size_t base = ((size_t)(b * P_ + pt * 64 + p)) * P_ + qt * 64;
  #pragma unroll
  for (int j = 0; j < 4; ++j) {
    int qb = ch * 16 + j * 4;
    f4 ssum = unpack4(*reinterpret_cast<const ushort4*>(&red[0][p][qb]));
    #pragma unroll
    for (int w = 1; w < 4; ++w)
      ssum += unpack4(*reinterpret_cast<const ushort4*>(&red[w][p][qb]));
    f4 rc;
    #pragma unroll
    for (int c = 0; c < 4; ++c) rc[c] = __builtin_amdgcn_rcpf(ssum[c]);
    *reinterpret_cast<uint2*>(recip + base + qb) = pack4(rc);
  }
}

// ---------------- attention pass 2 (prefetched) ----------------
__global__ __launch_bounds__(256) void attn_out_k(const u16* __restrict__ Q,
                                                  const u16* __restrict__ Km,
                                                  const u16* __restrict__ Vt,
                                                  const u16* __restrict__ recip,
                                                  const float* __restrict__ xin,
                                                  float* __restrict__ x2) {
  int pt = blockIdx.x, h = blockIdx.y, b = blockIdx.z;
  int wave = threadIdx.x >> 6, lane = threadIdx.x & 63, l15 = lane & 15, quad = lane >> 4;
  __shared__ __align__(16) u16 smem[4][64][72];
  u16(*albuf)[72] = smem[wave];

  const u16* Qp = Q + ((size_t)(b * H_ + h) * P_ + pt * 64) * HD_;
  const u16* Kbase = Km + (size_t)(b * H_ + h) * P_ * HD_;
  const u16* Vbase = Vt + (size_t)(b * H_ + h) * HD_ * P_;
  const u16* rbase = recip + ((size_t)(b * P_) + pt * 64) * P_;

  bf8 qf[4][2];
  #pragma unroll
  for (int nt = 0; nt < 4; ++nt)
    #pragma unroll
    for (int ks = 0; ks < 2; ++ks)
      qf[nt][ks] = *reinterpret_cast<const bf8*>(Qp + (size_t)(nt * 16 + l15) * 64 + ks * 32 + quad * 8);

  f4 oacc[4][4];
  ZERO44(oacc);

  for (int qt = wave; qt < P_ / 64; qt += 4) {
    const u16* Kp = Kbase + (size_t)qt * 64 * HD_;
    // batch-prefetch all K fragments for this tile (8 VMEM in flight)
    bf8 kf[4][2];
    #pragma unroll
    for (int mt = 0; mt < 4; ++mt)
      #pragma unroll
      for (int ks = 0; ks < 2; ++ks)
        kf[mt][ks] = *reinterpret_cast<const bf8*>(Kp + (size_t)(mt * 16 + l15) * 64 + ks * 32 + quad * 8);
    #pragma unroll
    for (int mt = 0; mt < 4; ++mt) {
      // hoist recip loads ahead of the MFMAs that feed their consumers
      ushort4 rv[4];
      #pragma unroll
      for (int nt = 0; nt < 4; ++nt)
        rv[nt] = *reinterpret_cast<const ushort4*>(rbase + (size_t)(nt * 16 + l15) * P_ +
                                                   qt * 64 + mt * 16 + quad * 4);
      f4 s[4];
      #pragma unroll
      for (int nt = 0; nt < 4; ++nt) s[nt] = f4{0.f, 0.f, 0.f, 0.f};
      #pragma unroll
      for (int ks = 0; ks < 2; ++ks)
        #pragma unroll
        for (int nt = 0; nt < 4; ++nt)
          s[nt] = mfma16(kf[mt][ks], qf[nt][ks], s[nt]);
      #pragma unroll
      for (int nt = 0; nt < 4; ++nt) {
        f4 a;
        a[0] = __builtin_amdgcn_exp2f(s[nt][0] * EXPC_) * bf2f(rv[nt].x);
        a[1] = __builtin_amdgcn_exp2f(s[nt][1] * EXPC_) * bf2f(rv[nt].y);
        a[2] = __builtin_amdgcn_exp2f(s[nt][2] * EXPC_) * bf2f(rv[nt].z);
        a[3] = __builtin_amdgcn_exp2f(s[nt][3] * EXPC_) * bf2f(rv[nt].w);
        *reinterpret_cast<uint2*>(&albuf[nt * 16 + l15][mt * 16 + quad * 4]) = pack4(a);
      }
    }
    // batch V fragment loads; they fly while the albuf writes drain
    bf8 vf[4][2];
    #pragma unroll
    for (int dt = 0; dt < 4; ++dt)
      #pragma unroll
      for (int ks = 0; ks < 2; ++ks)
        vf[dt][ks] = *reinterpret_cast<const bf8*>(Vbase + (size_t)(dt * 16 + l15) * P_ +
                                                   qt * 64 + ks * 32 + quad * 8);
    #pragma unroll
    for (int ks = 0; ks < 2; ++ks) {
      bf8 af[4];
      #pragma unroll
      for (int pi = 0; pi < 4; ++pi)
        af[pi] = *reinterpret_cast<const bf8*>(&albuf[pi * 16 + l15][ks * 32 + quad * 8]);
      #pragma unroll
      for (int dt = 0; dt < 4; ++dt)
        #pragma unroll
        for (int pi = 0; pi < 4; ++pi)
          oacc[dt][pi] = mfma16(vf[dt][ks], af[pi], oacc[dt][pi]);
    }
  }
  #pragma unroll
  for (int dt = 0; dt < 4; ++dt)
    #pragma unroll
    for (int pi = 0; pi < 4; ++pi)
      *reinterpret_cast<uint2*>(&smem[wave][pi * 16 + l15][dt * 16 + quad * 4]) = pack4(oacc[dt][pi]);
  __syncthreads();
  int p = threadIdx.x >> 2, ch = threadIdx.x & 3;
  size_t go = ((size_t)(b * P_) + pt * 64 + p) * D_ + h * 64;
  #pragma unroll
  for (int j = 0; j < 4; ++j) {
    int db = ch * 16 + j * 4;
    f4 o = unpack4(*reinterpret_cast<const ushort4*>(&smem[0][p][db]));
    #pragma unroll
    for (int w = 1; w < 4; ++w)
      o += unpack4(*reinterpret_cast<const ushort4*>(&smem[w][p][db]));
    f4 xv = *reinterpret_cast<const f4*>(xin + go + db);
    *reinterpret_cast<f4*>(x2 + go + db) = o + xv;
  }
}

extern "C" void kernel_launch(void* const* d_in, const int* in_sizes, int n_in,
                              void* d_out, int out_size, void* d_ws, size_t ws_size,
                              hipStream_t stream) {
  const float* x = (const float*)d_in[0];
  const float* ln1w = (const float*)d_in[1];
  const float* ln1b = (const float*)d_in[2];
  const float* wqkv = (const float*)d_in[3];
  const float* bqkv = (const float*)d_in[4];
  const float* ln2w = (const float*)d_in[5];
  const float* ln2b = (const float*)d_in[6];
  const float* wfc1 = (const float*)d_in[7];
  const float* bfc1 = (const float*)d_in[8];
  const float* wfc2 = (const float*)d_in[9];
  const float* bfc2 = (const float*)d_in[10];
  float* out = (float*)d_out;

  char* ws = (char*)d_ws;
  size_t off = 0;
  auto alloc = [&](size_t bytes) -> void* {
    void* p = ws + off;
    off += (bytes + 255) & ~(size_t)255;
    return p;
  };
  u16* hln = (u16*)alloc((size_t)8192 * 768 * 2);
  u16* wqkvT = (u16*)alloc((size_t)2304 * 768 * 2);
  u16* wfc1T = (u16*)alloc((size_t)3072 * 768 * 2);
  u16* wfc2T = (u16*)alloc((size_t)768 * 3072 * 2);
  u16* Qb = (u16*)alloc((size_t)B_ * H_ * P_ * HD_ * 2);
  u16* Kb = (u16*)alloc((size_t)B_ * H_ * P_ * HD_ * 2);
  u16* Vtb = (u16*)alloc((size_t)B_ * H_ * HD_ * P_ * 2);
  float* x2 = (float*)alloc((size_t)8192 * 768 * 4);
  u16* recip = (u16*)alloc((size_t)B_ * P_ * P_ * 4);  // bf16 recip, reused as fc1 out
  u16* g = recip;

  tcast_k<<<dim3(72, 24), 256, 0, stream>>>(wqkv, wqkvT, 768, 2304);
  tcast_k<<<dim3(96, 24), 256, 0, stream>>>(wfc1, wfc1T, 768, 3072);
  tcast_k<<<dim3(24, 96), 256, 0, stream>>>(wfc2, wfc2T, 3072, 768);
  ln_k<<<8192, 256, 0, stream>>>(x, ln1w, ln1b, hln);
  gemm_qkv_k<<<dim3(18, 64), 256, 0, stream>>>(hln, wqkvT, bqkv, Qb, Kb, Vtb);
  attn_denom_k<<<dim3(32, 32, 4), 256, 0, stream>>>(Qb, Kb, recip);
  attn_out_k<<<dim3(32, 12, 4), 256, 0, stream>>>(Qb, Kb, Vtb, recip, x, x2);
  ln_k<<<8192, 256, 0, stream>>>(x2, ln2w, ln2b, hln);
  gemm_fc1_k<<<dim3(24, 64), 256, 0, stream>>>(hln, wfc1T, bfc1, g);
  gemm_fc2_k<<<dim3(12, 64), 256, 0, stream>>>(g, wfc2T, bfc2, x2, out);
}

// Round 5
// 567.221 us; speedup vs baseline: 1.7404x; 1.1055x over previous
//
#include <hip/hip_runtime.h>
#include <hip/hip_bf16.h>

typedef __bf16 bf8 __attribute__((ext_vector_type(8)));
typedef float f4 __attribute__((ext_vector_type(4)));
typedef unsigned short u16;
typedef unsigned int u32;

#define B_ 4
#define P_ 2048
#define D_ 768
#define H_ 12
#define HD_ 64
#define PT_ 32
// scale * log2(e): exp(s*0.125) = exp2(s * 0.18033688)
#define EXPC_ 0.18033688011112042f

typedef const __attribute__((address_space(1))) void gvoid;
typedef __attribute__((address_space(3))) void lvoid;

__device__ __forceinline__ void gl_lds16(const u16* g, u16* l) {
  __builtin_amdgcn_global_load_lds((gvoid*)g, (lvoid*)l, 16, 0, 0);
}

__device__ __forceinline__ u16 f2bf(float f) {  // RNE
  union { float f; u32 u; } c; c.f = f;
  u32 u = c.u;
  u += 0x7fffu + ((u >> 16) & 1u);
  return (u16)(u >> 16);
}

__device__ __forceinline__ float bf2f(u16 v) {
  union { u32 u; float f; } c; c.u = (u32)v << 16; return c.f;
}

__device__ __forceinline__ uint2 pack4(f4 v) {  // truncating 4xf32 -> 4xbf16
  union { float f; u32 u; } a, b, c, d;
  a.f = v[0]; b.f = v[1]; c.f = v[2]; d.f = v[3];
  uint2 r;
  r.x = (a.u >> 16) | (b.u & 0xffff0000u);
  r.y = (c.u >> 16) | (d.u & 0xffff0000u);
  return r;
}

__device__ __forceinline__ f4 unpack4(ushort4 v) {
  f4 r;
  r[0] = bf2f(v.x); r[1] = bf2f(v.y); r[2] = bf2f(v.z); r[3] = bf2f(v.w);
  return r;
}

__device__ __forceinline__ f4 mfma16(bf8 a, bf8 b, f4 c) {
  return __builtin_amdgcn_mfma_f32_16x16x32_bf16(a, b, c, 0, 0, 0);
}

#define ZERO44(acc)                    \
  {                                    \
    f4 z_ = {0.f, 0.f, 0.f, 0.f};      \
    for (int i_ = 0; i_ < 4; ++i_)     \
      for (int j_ = 0; j_ < 4; ++j_)   \
        acc[i_][j_] = z_;              \
  }

// ---------------- transpose-cast fp32 (R,C) -> bf16 (C,R) ----------------
__global__ __launch_bounds__(256) void tcast_k(const float* __restrict__ src,
                                               u16* __restrict__ dst, int R, int C) {
  __shared__ float t[32][33];
  int c0 = blockIdx.x * 32, r0 = blockIdx.y * 32;
  int tx = threadIdx.x & 31, ty = threadIdx.x >> 5;
  #pragma unroll
  for (int i = 0; i < 32; i += 8) {
    int r = r0 + ty + i, c = c0 + tx;
    t[ty + i][tx] = (r < R && c < C) ? src[(size_t)r * C + c] : 0.f;
  }
  __syncthreads();
  #pragma unroll
  for (int i = 0; i < 32; i += 8) {
    int c = c0 + ty + i, r = r0 + tx;
    if (c < C && r < R) dst[(size_t)c * R + r] = f2bf(t[tx][ty + i]);
  }
}

// ---------------- layernorm fp32 -> bf16 ----------------
__global__ __launch_bounds__(256) void ln_k(const float* __restrict__ x,
                                            const float* __restrict__ g,
                                            const float* __restrict__ b,
                                            u16* __restrict__ out) {
  int row = blockIdx.x;
  const float* xr = x + (size_t)row * D_;
  float v0 = xr[threadIdx.x], v1 = xr[threadIdx.x + 256], v2 = xr[threadIdx.x + 512];
  float s = v0 + v1 + v2;
  float s2 = v0 * v0 + v1 * v1 + v2 * v2;
  #pragma unroll
  for (int o = 32; o > 0; o >>= 1) {
    s += __shfl_down(s, o, 64);
    s2 += __shfl_down(s2, o, 64);
  }
  __shared__ float a[4], a2[4];
  int wv = threadIdx.x >> 6;
  if ((threadIdx.x & 63) == 0) { a[wv] = s; a2[wv] = s2; }
  __syncthreads();
  s = a[0] + a[1] + a[2] + a[3];
  s2 = a2[0] + a2[1] + a2[2] + a2[3];
  float mean = s * (1.f / 768.f);
  float var = s2 * (1.f / 768.f) - mean * mean;
  float rstd = rsqrtf(var + 1e-5f);
  u16* orow = out + (size_t)row * D_;
  float vv[3] = {v0, v1, v2};
  #pragma unroll
  for (int j = 0; j < 3; ++j) {
    int i = threadIdx.x + j * 256;
    orow[i] = f2bf((vv[j] - mean) * rstd * g[i] + b[i]);
  }
}

// ============ staged 128x128 GEMM core (m97 pattern), K-stride 32 ============
template <int K>
__device__ __forceinline__ void staged_core(const u16* __restrict__ Ab,
                                            const u16* __restrict__ Bb,
                                            u16* As, u16* Bs, f4 acc[4][4]) {
  const int wave = threadIdx.x >> 6, lane = threadIdx.x & 63;
  const int l15 = lane & 15, quad = lane >> 4;
  const int lrow = lane >> 2;
  const int lcol = (lane & 3) * 8;
  const int mw = (wave & 1) * 64, nw = (wave >> 1) * 64;
  for (int k0 = 0; k0 < K; k0 += 32) {
    const u16* ga = Ab + (size_t)(wave * 32 + lrow) * K + k0 + lcol;
    gl_lds16(ga, &As[(wave * 32) * 32]);
    gl_lds16(ga + (size_t)16 * K, &As[(wave * 32 + 16) * 32]);
    const u16* gb = Bb + (size_t)(wave * 32 + lrow) * K + k0 + lcol;
    gl_lds16(gb, &Bs[(wave * 32) * 32]);
    gl_lds16(gb + (size_t)16 * K, &Bs[(wave * 32 + 16) * 32]);
    __syncthreads();
    bf8 a[4], b[4];
    #pragma unroll
    for (int mt = 0; mt < 4; ++mt)
      a[mt] = *reinterpret_cast<const bf8*>(&As[(mw + mt * 16 + l15) * 32 + quad * 8]);
    #pragma unroll
    for (int nt = 0; nt < 4; ++nt)
      b[nt] = *reinterpret_cast<const bf8*>(&Bs[(nw + nt * 16 + l15) * 32 + quad * 8]);
    #pragma unroll
    for (int mt = 0; mt < 4; ++mt)
      #pragma unroll
      for (int nt = 0; nt < 4; ++nt)
        acc[mt][nt] = mfma16(a[mt], b[nt], acc[mt][nt]);
    __syncthreads();
  }
}

// ---------------- QKV GEMM staged ----------------
__global__ __launch_bounds__(256) void gemm_qkv_k(const u16* __restrict__ hln,
                                                  const u16* __restrict__ wT,
                                                  const float* __restrict__ bias,
                                                  u16* __restrict__ Q, u16* __restrict__ Km,
                                                  u16* __restrict__ Vt) {
  __shared__ u16 As[128 * 32], Bs[128 * 32];
  int m0 = blockIdx.y * 128, n0 = blockIdx.x * 128;
  f4 acc[4][4];
  ZERO44(acc);
  staged_core<768>(hln + (size_t)m0 * 768, wT + (size_t)n0 * 768, As, Bs, acc);
  int wave = threadIdx.x >> 6, lane = threadIdx.x & 63, l15 = lane & 15, quad = lane >> 4;
  int mW = m0 + (wave & 1) * 64, nW = n0 + (wave >> 1) * 64;
  #pragma unroll
  for (int mt = 0; mt < 4; ++mt)
    #pragma unroll
    for (int nt = 0; nt < 4; ++nt)
      #pragma unroll
      for (int r = 0; r < 4; ++r) {
        int m = mW + mt * 16 + quad * 4 + r;
        int n = nW + nt * 16 + l15;
        float v = acc[mt][nt][r] + bias[n];
        u16 bv = f2bf(v);
        int b = m >> 11, p = m & 2047;
        int which = n / 768, hn = n % 768;
        int h = hn >> 6, d = hn & 63;
        if (which == 0)
          Q[((size_t)(b * H_ + h) * P_ + p) * HD_ + d] = bv;
        else if (which == 1)
          Km[((size_t)(b * H_ + h) * P_ + p) * HD_ + d] = bv;
        else
          Vt[((size_t)(b * H_ + h) * HD_ + d) * P_ + p] = bv;
      }
}

// ---------------- FC1 GEMM staged + exact GELU ----------------
__global__ __launch_bounds__(256) void gemm_fc1_k(const u16* __restrict__ A,
                                                  const u16* __restrict__ wT,
                                                  const float* __restrict__ bias,
                                                  u16* __restrict__ out) {
  __shared__ u16 As[128 * 32], Bs[128 * 32];
  int m0 = blockIdx.y * 128, n0 = blockIdx.x * 128;
  f4 acc[4][4];
  ZERO44(acc);
  staged_core<768>(A + (size_t)m0 * 768, wT + (size_t)n0 * 768, As, Bs, acc);
  int wave = threadIdx.x >> 6, lane = threadIdx.x & 63, l15 = lane & 15, quad = lane >> 4;
  int mW = m0 + (wave & 1) * 64, nW = n0 + (wave >> 1) * 64;
  #pragma unroll
  for (int mt = 0; mt < 4; ++mt)
    #pragma unroll
    for (int nt = 0; nt < 4; ++nt)
      #pragma unroll
      for (int r = 0; r < 4; ++r) {
        int m = mW + mt * 16 + quad * 4 + r;
        int n = nW + nt * 16 + l15;
        float v = acc[mt][nt][r] + bias[n];
        v = 0.5f * v * (1.f + erff(v * 0.70710678f));
        out[(size_t)m * 3072 + n] = f2bf(v);
      }
}

// ---------------- FC2 GEMM staged (BM=128, BN=64), +bias +residual -> fp32 ----------------
__global__ __launch_bounds__(256) void gemm_fc2_k(const u16* __restrict__ A,
                                                  const u16* __restrict__ wT,
                                                  const float* __restrict__ bias,
                                                  const float* __restrict__ resid,
                                                  float* __restrict__ out) {
  __shared__ u16 As[128 * 32], Bs[64 * 32];
  int wave = threadIdx.x >> 6, lane = threadIdx.x & 63, l15 = lane & 15, quad = lane >> 4;
  int lrow = lane >> 2, lcol = (lane & 3) * 8;
  int m0 = blockIdx.y * 128, n0 = blockIdx.x * 64;
  const u16* Ab = A + (size_t)m0 * 3072;
  const u16* Bb = wT + (size_t)n0 * 3072;
  int mw = (wave & 1) * 64, nw = (wave >> 1) * 32;
  f4 acc[4][2];
  #pragma unroll
  for (int i = 0; i < 4; ++i)
    #pragma unroll
    for (int j = 0; j < 2; ++j) acc[i][j] = f4{0.f, 0.f, 0.f, 0.f};
  for (int k0 = 0; k0 < 3072; k0 += 32) {
    const u16* ga = Ab + (size_t)(wave * 32 + lrow) * 3072 + k0 + lcol;
    gl_lds16(ga, &As[(wave * 32) * 32]);
    gl_lds16(ga + (size_t)16 * 3072, &As[(wave * 32 + 16) * 32]);
    const u16* gb = Bb + (size_t)(wave * 16 + lrow) * 3072 + k0 + lcol;
    gl_lds16(gb, &Bs[(wave * 16) * 32]);
    __syncthreads();
    bf8 a[4], b[2];
    #pragma unroll
    for (int mt = 0; mt < 4; ++mt)
      a[mt] = *reinterpret_cast<const bf8*>(&As[(mw + mt * 16 + l15) * 32 + quad * 8]);
    #pragma unroll
    for (int nt = 0; nt < 2; ++nt)
      b[nt] = *reinterpret_cast<const bf8*>(&Bs[(nw + nt * 16 + l15) * 32 + quad * 8]);
    #pragma unroll
    for (int mt = 0; mt < 4; ++mt)
      #pragma unroll
      for (int nt = 0; nt < 2; ++nt)
        acc[mt][nt] = mfma16(a[mt], b[nt], acc[mt][nt]);
    __syncthreads();
  }
  int mW = m0 + mw, nW = n0 + nw;
  #pragma unroll
  for (int mt = 0; mt < 4; ++mt)
    #pragma unroll
    for (int nt = 0; nt < 2; ++nt)
      #pragma unroll
      for (int r = 0; r < 4; ++r) {
        int m = mW + mt * 16 + quad * 4 + r;
        int n = nW + nt * 16 + l15;
        size_t idx = (size_t)m * 768 + n;
        out[idx] = acc[mt][nt][r] + bias[n] + resid[idx];
      }
}

// ======== fused attention: all 12 heads per block, softmax over heads ========
// Block = (pt: 32 p-rows, b). 768 threads = 12 waves; wave w <-> head w.
// Per 64-wide q-tile: each wave computes S^T (M=q64, N=p32), exp -> LDS E[h][p][q],
// then D = sum_h E and E <- E * rcp(D) in place, then O^T += V^T-frag @ A-frag.
__global__ __launch_bounds__(768) void attn_fused_k(const u16* __restrict__ Q,
                                                    const u16* __restrict__ Km,
                                                    const u16* __restrict__ Vt,
                                                    const float* __restrict__ xin,
                                                    float* __restrict__ x2) {
  int pt = blockIdx.x, b = blockIdx.y;
  int w = threadIdx.x >> 6;  // wave == head
  int lane = threadIdx.x & 63, l15 = lane & 15, quad = lane >> 4;
  __shared__ __align__(16) u16 E[12][PT_][72];  // 55.3 KB

  const u16* Qp = Q + ((size_t)(b * H_ + w) * P_ + pt * PT_) * HD_;
  const u16* Kbase = Km + (size_t)(b * H_ + w) * P_ * HD_;
  const u16* Vbase = Vt + (size_t)(b * H_ + w) * HD_ * P_;

  // Q fragments for this wave's head, 32 p-rows (persist across all q-tiles)
  bf8 qf[2][2];
  #pragma unroll
  for (int nt = 0; nt < 2; ++nt)
    #pragma unroll
    for (int ks = 0; ks < 2; ++ks)
      qf[nt][ks] = *reinterpret_cast<const bf8*>(Qp + (size_t)(nt * 16 + l15) * HD_ + ks * 32 + quad * 8);

  f4 oacc[4][2];  // O^T: d (4x16) x p (2x16)
  #pragma unroll
  for (int i = 0; i < 4; ++i)
    #pragma unroll
    for (int j = 0; j < 2; ++j) oacc[i][j] = f4{0.f, 0.f, 0.f, 0.f};

  for (int qt = 0; qt < P_ / 64; ++qt) {
    const u16* Kp = Kbase + (size_t)qt * 64 * HD_;
    // --- S^T + exp -> E[w] ---
    f4 s[4][2];
    #pragma unroll
    for (int i = 0; i < 4; ++i) {
      s[i][0] = f4{0.f, 0.f, 0.f, 0.f};
      s[i][1] = f4{0.f, 0.f, 0.f, 0.f};
    }
    #pragma unroll
    for (int mt = 0; mt < 4; ++mt) {
      bf8 kf0 = *reinterpret_cast<const bf8*>(Kp + (size_t)(mt * 16 + l15) * HD_ + quad * 8);
      bf8 kf1 = *reinterpret_cast<const bf8*>(Kp + (size_t)(mt * 16 + l15) * HD_ + 32 + quad * 8);
      #pragma unroll
      for (int nt = 0; nt < 2; ++nt) {
        s[mt][nt] = mfma16(kf0, qf[nt][0], s[mt][nt]);
        s[mt][nt] = mfma16(kf1, qf[nt][1], s[mt][nt]);
      }
    }
    #pragma unroll
    for (int mt = 0; mt < 4; ++mt)
      #pragma unroll
      for (int nt = 0; nt < 2; ++nt) {
        f4 e;
        #pragma unroll
        for (int r = 0; r < 4; ++r) e[r] = __builtin_amdgcn_exp2f(s[mt][nt][r] * EXPC_);
        *reinterpret_cast<uint2*>(&E[w][nt * 16 + l15][mt * 16 + quad * 4]) = pack4(e);
      }
    __syncthreads();
    // --- D = sum_h E; E <- E * rcp(D), in place (threads 0..255) ---
    if (threadIdx.x < 256) {
      int p = threadIdx.x >> 3, q0 = (threadIdx.x & 7) * 8;
      ushort4 eh[12][2];
      f4 sum0 = {0.f, 0.f, 0.f, 0.f}, sum1 = {0.f, 0.f, 0.f, 0.f};
      #pragma unroll
      for (int h = 0; h < 12; ++h) {
        eh[h][0] = *reinterpret_cast<const ushort4*>(&E[h][p][q0]);
        eh[h][1] = *reinterpret_cast<const ushort4*>(&E[h][p][q0 + 4]);
        sum0 += unpack4(eh[h][0]);
        sum1 += unpack4(eh[h][1]);
      }
      f4 r0, r1;
      #pragma unroll
      for (int c = 0; c < 4; ++c) {
        r0[c] = __builtin_amdgcn_rcpf(sum0[c]);
        r1[c] = __builtin_amdgcn_rcpf(sum1[c]);
      }
      #pragma unroll
      for (int h = 0; h < 12; ++h) {
        *reinterpret_cast<uint2*>(&E[h][p][q0]) = pack4(unpack4(eh[h][0]) * r0);
        *reinterpret_cast<uint2*>(&E[h][p][q0 + 4]) = pack4(unpack4(eh[h][1]) * r1);
      }
    }
    __syncthreads();
    // --- O^T += V^T-frag @ A-frag ---
    #pragma unroll
    for (int ks = 0; ks < 2; ++ks) {
      bf8 af0 = *reinterpret_cast<const bf8*>(&E[w][l15][ks * 32 + quad * 8]);
      bf8 af1 = *reinterpret_cast<const bf8*>(&E[w][16 + l15][ks * 32 + quad * 8]);
      #pragma unroll
      for (int dt = 0; dt < 4; ++dt) {
        bf8 vf = *reinterpret_cast<const bf8*>(Vbase + (size_t)(dt * 16 + l15) * P_ +
                                               qt * 64 + ks * 32 + quad * 8);
        oacc[dt][0] = mfma16(vf, af0, oacc[dt][0]);
        oacc[dt][1] = mfma16(vf, af1, oacc[dt][1]);
      }
    }
    __syncthreads();  // protect E before next tile's writes
  }
  // --- O^T (bf16) -> LDS, then coalesced +residual write ---
  #pragma unroll
  for (int dt = 0; dt < 4; ++dt)
    #pragma unroll
    for (int pi = 0; pi < 2; ++pi)
      *reinterpret_cast<uint2*>(&E[w][pi * 16 + l15][dt * 16 + quad * 4]) = pack4(oacc[dt][pi]);
  __syncthreads();
  int m = threadIdx.x % 24, p = threadIdx.x / 24;  // p 0..31, 24 col-chunks of 32
  int h = m >> 1, d0 = (m & 1) * 32;
  size_t go = ((size_t)(b * P_) + pt * PT_ + p) * D_ + h * 64 + d0;
  #pragma unroll
  for (int j = 0; j < 8; ++j) {
    f4 o = unpack4(*reinterpret_cast<const ushort4*>(&E[h][p][d0 + j * 4]));
    f4 xv = *reinterpret_cast<const f4*>(xin + go + j * 4);
    *reinterpret_cast<f4*>(x2 + go + j * 4) = o + xv;
  }
}

extern "C" void kernel_launch(void* const* d_in, const int* in_sizes, int n_in,
                              void* d_out, int out_size, void* d_ws, size_t ws_size,
                              hipStream_t stream) {
  const float* x = (const float*)d_in[0];
  const float* ln1w = (const float*)d_in[1];
  const float* ln1b = (const float*)d_in[2];
  const float* wqkv = (const float*)d_in[3];
  const float* bqkv = (const float*)d_in[4];
  const float* ln2w = (const float*)d_in[5];
  const float* ln2b = (const float*)d_in[6];
  const float* wfc1 = (const float*)d_in[7];
  const float* bfc1 = (const float*)d_in[8];
  const float* wfc2 = (const float*)d_in[9];
  const float* bfc2 = (const float*)d_in[10];
  float* out = (float*)d_out;

  char* ws = (char*)d_ws;
  size_t off = 0;
  auto alloc = [&](size_t bytes) -> void* {
    void* p = ws + off;
    off += (bytes + 255) & ~(size_t)255;
    return p;
  };
  u16* hln = (u16*)alloc((size_t)8192 * 768 * 2);
  u16* wqkvT = (u16*)alloc((size_t)2304 * 768 * 2);
  u16* wfc1T = (u16*)alloc((size_t)3072 * 768 * 2);
  u16* wfc2T = (u16*)alloc((size_t)768 * 3072 * 2);
  u16* Qb = (u16*)alloc((size_t)B_ * H_ * P_ * HD_ * 2);
  u16* Kb = (u16*)alloc((size_t)B_ * H_ * P_ * HD_ * 2);
  u16* Vtb = (u16*)alloc((size_t)B_ * H_ * HD_ * P_ * 2);
  float* x2 = (float*)alloc((size_t)8192 * 768 * 4);
  u16* g = (u16*)alloc((size_t)8192 * 3072 * 2);

  tcast_k<<<dim3(72, 24), 256, 0, stream>>>(wqkv, wqkvT, 768, 2304);
  tcast_k<<<dim3(96, 24), 256, 0, stream>>>(wfc1, wfc1T, 768, 3072);
  tcast_k<<<dim3(24, 96), 256, 0, stream>>>(wfc2, wfc2T, 3072, 768);
  ln_k<<<8192, 256, 0, stream>>>(x, ln1w, ln1b, hln);
  gemm_qkv_k<<<dim3(18, 64), 256, 0, stream>>>(hln, wqkvT, bqkv, Qb, Kb, Vtb);
  attn_fused_k<<<dim3(64, 4), 768, 0, stream>>>(Qb, Kb, Vtb, x, x2);
  ln_k<<<8192, 256, 0, stream>>>(x2, ln2w, ln2b, hln);
  gemm_fc1_k<<<dim3(24, 64), 256, 0, stream>>>(hln, wfc1T, bfc1, g);
  gemm_fc2_k<<<dim3(12, 64), 256, 0, stream>>>(g, wfc2T, bfc2, x2, out);
}